// Round 1
// baseline (1164.840 us; speedup 1.0000x reference)
//
#include <hip/hip_runtime.h>
#include <stdint.h>

#define N_ROWS 16384
#define DIM    512

typedef __bf16 v8bf __attribute__((ext_vector_type(8)));
typedef float  v4f  __attribute__((ext_vector_type(4)));
typedef unsigned long long u64;

union I4B8 { int4 i; v8bf b; };
__device__ __forceinline__ v8bf as_v8bf(int4 v) { I4B8 u; u.i = v; return u.b; }

// Round-to-nearest-even fp32 -> bf16 (bit trick; inputs are finite normals)
__device__ __forceinline__ ushort bf16_rne(float f) {
    unsigned u = __float_as_uint(f);
    unsigned r = u + 0x7FFFu + ((u >> 16) & 1u);
    return (ushort)(r >> 16);
}

// Monotonic float -> sortable u32 key
__device__ __forceinline__ unsigned fkey(float f) {
    unsigned u = __float_as_uint(f);
    return (u & 0x80000000u) ? ~u : (u | 0x80000000u);
}

// ---------------- kernel 1: fp32 -> bf16 convert ----------------
__global__ __launch_bounds__(256)
void convert_bf16_kernel(const float* __restrict__ x, ushort* __restrict__ xb) {
    int tid    = blockIdx.x * blockDim.x + threadIdx.x;
    int stride = gridDim.x * blockDim.x;
    const float4* x4  = (const float4*)x;
    ushort4*      xb4 = (ushort4*)xb;
    const int n4 = (N_ROWS * DIM) / 4;
    for (int i = tid; i < n4; i += stride) {
        float4 v = x4[i];
        ushort4 o;
        o.x = bf16_rne(v.x);
        o.y = bf16_rne(v.y);
        o.z = bf16_rne(v.z);
        o.w = bf16_rne(v.w);
        xb4[i] = o;
    }
}

// ---------------- kernel 2: fused dot-GEMM + row argmax ----------------
// Grid: 512 blocks x 256 threads. blockIdx>>3 = row block (256 rows, 64/wave),
// blockIdx&7 = column split (2048 cols) -> XCD-affine for L2 locality.
// Each wave: 64x64 C tile per col-iteration via 4x4 grid of 16x16x32 bf16 MFMA.
__global__ __launch_bounds__(256, 2)
void argmax_dots_kernel(const ushort* __restrict__ xb, u64* __restrict__ table) {
    const int lane   = threadIdx.x & 63;
    const int wave   = threadIdx.x >> 6;
    const int lane15 = lane & 15;
    const int quad   = lane >> 4;

    const int rowBlock = blockIdx.x >> 3;
    const int colSplit = blockIdx.x & 7;
    const int rbase = rowBlock * 256 + wave * 64;
    const int cb0   = colSplit * 2048;

    // Both A and B fragments: lane15 = row-within-frag, quad*8 = k offset,
    // 16 contiguous bytes per lane (verified m89/m91/m120 layouts).
    const ushort* pA  = xb + (size_t)(rbase + lane15) * DIM + quad * 8;
    const ushort* pB0 = xb + (size_t)(cb0   + lane15) * DIM + quad * 8;

    float best_val[4][4];   // [row-frag][reg] : 16 rows owned by this lane
    int   best_col[4][4];
#pragma unroll
    for (int rf = 0; rf < 4; ++rf)
#pragma unroll
        for (int e = 0; e < 4; ++e) { best_val[rf][e] = -3.0e38f; best_col[rf][e] = 0; }

    for (int ct = 0; ct < 32; ++ct) {          // 32 col tiles of 64 within this split
        const ushort* pB = pB0 + (size_t)ct * 64 * DIM;

        v4f acc[4][4];
#pragma unroll
        for (int rf = 0; rf < 4; ++rf)
#pragma unroll
            for (int cf = 0; cf < 4; ++cf) {
                v4f z = {0.f, 0.f, 0.f, 0.f};
                acc[rf][cf] = z;
            }

#pragma unroll 2
        for (int kk = 0; kk < DIM; kk += 32) {
            int4 ar[4], br[4];
#pragma unroll
            for (int rf = 0; rf < 4; ++rf)
                ar[rf] = *(const int4*)(pA + rf * 16 * DIM + kk);
#pragma unroll
            for (int cf = 0; cf < 4; ++cf)
                br[cf] = *(const int4*)(pB + cf * 16 * DIM + kk);
#pragma unroll
            for (int rf = 0; rf < 4; ++rf)
#pragma unroll
                for (int cf = 0; cf < 4; ++cf)
                    acc[rf][cf] = __builtin_amdgcn_mfma_f32_16x16x32_bf16(
                        as_v8bf(ar[rf]), as_v8bf(br[cf]), acc[rf][cf], 0, 0, 0);
        }

        // Running argmax update. C/D layout: col = lane&15, row = quad*4 + reg.
        const int cbase = cb0 + ct * 64 + lane15;
#pragma unroll
        for (int rf = 0; rf < 4; ++rf) {
            const int rowb = rbase + rf * 16 + quad * 4;
#pragma unroll
            for (int cf = 0; cf < 4; ++cf) {
                const int col = cbase + cf * 16;
#pragma unroll
                for (int e = 0; e < 4; ++e) {
                    float v = acc[rf][cf][e];
                    if (v > best_val[rf][e] && col != rowb + e) {
                        best_val[rf][e] = v;
                        best_col[rf][e] = col;
                    }
                }
            }
        }
    }

    // Reduce across the 16 lanes of each quad (they hold the same rows,
    // different cols), then one atomicMax per row into the global table.
#pragma unroll
    for (int rf = 0; rf < 4; ++rf)
#pragma unroll
        for (int e = 0; e < 4; ++e) {
            u64 packed = ((u64)fkey(best_val[rf][e]) << 32) |
                         (unsigned)(~best_col[rf][e]);   // ~col: ties -> lowest index
#pragma unroll
            for (int m = 1; m < 16; m <<= 1) {
                u64 other = __shfl_xor(packed, m, 64);
                packed = (other > packed) ? other : packed;
            }
            if (lane15 == 0) {
                int row = rbase + rf * 16 + quad * 4 + e;
                atomicMax(&table[row], packed);
            }
        }
}

// ---------------- kernel 3: rho + loss epilogue (fp32 exact) ----------------
// 512 blocks x 256 threads; one wave per row, 8 rows per wave.
__global__ __launch_bounds__(256)
void rho_loss_kernel(const float* __restrict__ x, const u64* __restrict__ table,
                     float* __restrict__ out) {
    const int lane = threadIdx.x & 63;
    const int wave = threadIdx.x >> 6;
    const int waveGlobal = blockIdx.x * 4 + wave;   // 2048 waves

    float local = 0.f;
    for (int r8 = 0; r8 < 8; ++r8) {
        const int row = waveGlobal * 8 + r8;
        const u64 packed = table[row];
        const int nb = (int)(~(unsigned)(packed & 0xFFFFFFFFu));

        const float4* xr = (const float4*)(x + (size_t)row * DIM);
        const float4* xn = (const float4*)(x + (size_t)nb  * DIM);
        float s = 0.f;
#pragma unroll
        for (int t = 0; t < 2; ++t) {
            float4 a = xr[lane * 2 + t];
            float4 b = xn[lane * 2 + t];
            float d0 = a.x - b.x + 1e-6f;
            float d1 = a.y - b.y + 1e-6f;
            float d2 = a.z - b.z + 1e-6f;
            float d3 = a.w - b.w + 1e-6f;
            s += d0 * d0 + d1 * d1 + d2 * d2 + d3 * d3;
        }
#pragma unroll
        for (int m = 1; m < 64; m <<= 1) s += __shfl_xor(s, m, 64);

        if (lane == 0) {
            float rho = sqrtf(s);
            local += logf(rho + 1e-8f);
        }
    }
    if (lane == 0) atomicAdd(out, -local * (1.0f / 16384.0f));
}

extern "C" void kernel_launch(void* const* d_in, const int* in_sizes, int n_in,
                              void* d_out, int out_size, void* d_ws, size_t ws_size,
                              hipStream_t stream) {
    const float* x = (const float*)d_in[0];

    // Workspace layout: [0, 16 MiB) bf16 copy of x; then 16384 x u64 argmax table.
    ushort* xb   = (ushort*)d_ws;
    u64*   table = (u64*)((char*)d_ws + (size_t)N_ROWS * DIM * sizeof(ushort));
    float* out   = (float*)d_out;

    hipMemsetAsync(table, 0, N_ROWS * sizeof(u64), stream);
    hipMemsetAsync(out, 0, sizeof(float), stream);

    convert_bf16_kernel<<<2048, 256, 0, stream>>>(x, xb);
    argmax_dots_kernel<<<512, 256, 0, stream>>>(xb, table);
    rho_loss_kernel<<<512, 256, 0, stream>>>(x, table, out);
}

// Round 2
// 552.770 us; speedup vs baseline: 2.1073x; 2.1073x over previous
//
#include <hip/hip_runtime.h>
#include <stdint.h>

#define N_ROWS 16384
#define DIM    512

typedef __bf16 v8bf __attribute__((ext_vector_type(8)));
typedef float  v4f  __attribute__((ext_vector_type(4)));
typedef unsigned long long u64;

union I4B8 { int4 i; v8bf b; };
__device__ __forceinline__ v8bf as_v8bf(int4 v) { I4B8 u; u.i = v; return u.b; }

// Round-to-nearest-even fp32 -> bf16
__device__ __forceinline__ ushort bf16_rne(float f) {
    unsigned u = __float_as_uint(f);
    unsigned r = u + 0x7FFFu + ((u >> 16) & 1u);
    return (ushort)(r >> 16);
}

// Monotonic float -> sortable u32 key
__device__ __forceinline__ unsigned fkey(float f) {
    unsigned u = __float_as_uint(f);
    return (u & 0x80000000u) ? ~u : (u | 0x80000000u);
}

// Async global->LDS, 16B per lane. LDS dest = wave-uniform base + lane*16.
__device__ __forceinline__ void gload_lds16(const void* g, void* l) {
    __builtin_amdgcn_global_load_lds(
        (const __attribute__((address_space(1))) unsigned int*)g,
        (__attribute__((address_space(3))) unsigned int*)l,
        16, 0, 0);
}

// ---------------- kernel 1: fp32 -> bf16 convert ----------------
__global__ __launch_bounds__(256)
void convert_bf16_kernel(const float* __restrict__ x, ushort* __restrict__ xb) {
    int tid    = blockIdx.x * blockDim.x + threadIdx.x;
    int stride = gridDim.x * blockDim.x;
    const float4* x4  = (const float4*)x;
    ushort4*      xb4 = (ushort4*)xb;
    const int n4 = (N_ROWS * DIM) / 4;
    for (int i = tid; i < n4; i += stride) {
        float4 v = x4[i];
        ushort4 o;
        o.x = bf16_rne(v.x);
        o.y = bf16_rne(v.y);
        o.z = bf16_rne(v.z);
        o.w = bf16_rne(v.w);
        xb4[i] = o;
    }
}

// ---------------- kernel 2: symmetric tiled GEMM + fused argmax ----------------
// Grid 128x128 tiles (flat 16384 blocks); only rT <= cT computed (Gram symmetry).
// Block: 128x128 C tile, 4 waves in 2x2 quadrants of 64x64, BK=64 LDS staging
// via global_load_lds (width 16), m97 2-barrier K-loop.
// LDS chunk layout (16B chunks), linear index L in [0,1024):
//   half = L>>9, s = (L>>8)&1, rf = (L>>6)&3, quad = (L>>4)&3, lane15 = L&15
//   row(L) = half*64 + rf*16 + lane15 ;  kchunk(L) = s*4 + quad  (k = kchunk*8)
// => frag ds_read_b128 for (half,s,rf) is at base + lane*16: conflict-free.
__global__ __launch_bounds__(256)
void argmax_dots_kernel(const ushort* __restrict__ xb, u64* __restrict__ table) {
    __shared__ __attribute__((aligned(16))) ushort ldsA[128 * 64];  // 16 KB
    __shared__ __attribute__((aligned(16))) ushort ldsB[128 * 64];  // 16 KB

    const int rT = blockIdx.x >> 7;
    const int cT = blockIdx.x & 127;
    if (rT > cT) return;                    // symmetry: upper triangle only

    const int t      = threadIdx.x;
    const int lane   = t & 63;
    const int wave   = t >> 6;
    const int lane15 = lane & 15;
    const int quad   = lane >> 4;
    const int rh = wave >> 1;               // row half of the 128x128 tile
    const int ch = wave & 1;                // col half

    const int rowBase = rT * 128;
    const int colBase = cT * 128;

    // Per-thread staging sources for the 4 issues per matrix per round.
    const ushort* gA[4];
    const ushort* gB[4];
#pragma unroll
    for (int j = 0; j < 4; ++j) {
        const int L = j * 256 + t;
        const int srow = ((L >> 9) << 6) + (((L >> 6) & 3) << 4) + (L & 15);
        const int skc  = (((L >> 8) & 1) << 2) + ((L >> 4) & 3);
        gA[j] = xb + (size_t)(rowBase + srow) * DIM + skc * 8;
        gB[j] = xb + (size_t)(colBase + srow) * DIM + skc * 8;
    }
    const int dstOff = wave * 1024;         // + j*4096 per issue (bytes)

    v4f acc[4][4];
#pragma unroll
    for (int rf = 0; rf < 4; ++rf)
#pragma unroll
        for (int cf = 0; cf < 4; ++cf) {
            v4f z = {0.f, 0.f, 0.f, 0.f};
            acc[rf][cf] = z;
        }

    for (int kk = 0; kk < DIM; kk += 64) {  // 8 rounds
#pragma unroll
        for (int j = 0; j < 4; ++j) {
            gload_lds16(gA[j] + kk, (char*)ldsA + j * 4096 + dstOff);
            gload_lds16(gB[j] + kk, (char*)ldsB + j * 4096 + dstOff);
        }
        __syncthreads();                    // drains vmcnt, loads visible

#pragma unroll
        for (int s = 0; s < 2; ++s) {
            int4 ar[4], br[4];
#pragma unroll
            for (int rf = 0; rf < 4; ++rf)
                ar[rf] = *(const int4*)((const char*)ldsA + rh * 8192 + s * 4096 + rf * 1024 + lane * 16);
#pragma unroll
            for (int cf = 0; cf < 4; ++cf)
                br[cf] = *(const int4*)((const char*)ldsB + ch * 8192 + s * 4096 + cf * 1024 + lane * 16);
#pragma unroll
            for (int rf = 0; rf < 4; ++rf)
#pragma unroll
                for (int cf = 0; cf < 4; ++cf)
                    acc[rf][cf] = __builtin_amdgcn_mfma_f32_16x16x32_bf16(
                        as_v8bf(ar[rf]), as_v8bf(br[cf]), acc[rf][cf], 0, 0, 0);
        }
        __syncthreads();                    // protect LDS from next round's writes
    }

    // ---- epilogue: row-side argmax (C/D layout: col=lane15+16*cf, row=quad*4+e) ----
    const int colLane = colBase + ch * 64 + lane15;
#pragma unroll
    for (int rf = 0; rf < 4; ++rf) {
#pragma unroll
        for (int e = 0; e < 4; ++e) {
            const int row = rowBase + rh * 64 + rf * 16 + quad * 4 + e;
            float bv = -3.0e38f;
            int   bc = 0;
#pragma unroll
            for (int cf = 0; cf < 4; ++cf) {
                const float v = acc[rf][cf][e];
                const int col = colLane + cf * 16;
                if (v > bv && col != row) { bv = v; bc = col; }
            }
            u64 packed = ((u64)fkey(bv) << 32) | (unsigned)(~bc);  // ~col: ties -> lowest idx
#pragma unroll
            for (int m = 1; m < 16; m <<= 1) {
                u64 o = __shfl_xor(packed, m, 64);
                if (o > packed) packed = o;
            }
            if (lane15 == 0) atomicMax(&table[row], packed);
        }
    }

    // ---- epilogue: col-side (transposed) argmax for off-diagonal tiles ----
    if (rT != cT) {
#pragma unroll
        for (int cf = 0; cf < 4; ++cf) {
            const int col = colLane + cf * 16;
            float bv = -3.0e38f;
            int   br_ = 0;
#pragma unroll
            for (int rf = 0; rf < 4; ++rf)
#pragma unroll
                for (int e = 0; e < 4; ++e) {
                    const float v = acc[rf][cf][e];
                    const int row = rowBase + rh * 64 + rf * 16 + quad * 4 + e;
                    if (v > bv) { bv = v; br_ = row; }   // row != col off-diagonal
                }
            u64 packed = ((u64)fkey(bv) << 32) | (unsigned)(~br_);
            u64 o = __shfl_xor(packed, 16, 64); if (o > packed) packed = o;
            o     = __shfl_xor(packed, 32, 64); if (o > packed) packed = o;
            if (quad == 0) atomicMax(&table[col], packed);
        }
    }
}

// ---------------- kernel 3: rho + loss epilogue (fp32 exact) ----------------
__global__ __launch_bounds__(256)
void rho_loss_kernel(const float* __restrict__ x, const u64* __restrict__ table,
                     float* __restrict__ out) {
    const int lane = threadIdx.x & 63;
    const int wave = threadIdx.x >> 6;
    const int waveGlobal = blockIdx.x * 4 + wave;   // 2048 waves

    float local = 0.f;
    for (int r8 = 0; r8 < 8; ++r8) {
        const int row = waveGlobal * 8 + r8;
        const u64 packed = table[row];
        const int nb = (int)(~(unsigned)(packed & 0xFFFFFFFFu));

        const float4* xr = (const float4*)(x + (size_t)row * DIM);
        const float4* xn = (const float4*)(x + (size_t)nb  * DIM);
        float s = 0.f;
#pragma unroll
        for (int tt = 0; tt < 2; ++tt) {
            float4 a = xr[lane * 2 + tt];
            float4 b = xn[lane * 2 + tt];
            float d0 = a.x - b.x + 1e-6f;
            float d1 = a.y - b.y + 1e-6f;
            float d2 = a.z - b.z + 1e-6f;
            float d3 = a.w - b.w + 1e-6f;
            s += d0 * d0 + d1 * d1 + d2 * d2 + d3 * d3;
        }
#pragma unroll
        for (int m = 1; m < 64; m <<= 1) s += __shfl_xor(s, m, 64);

        if (lane == 0) {
            float rho = sqrtf(s);
            local += logf(rho + 1e-8f);
        }
    }
    if (lane == 0) atomicAdd(out, -local * (1.0f / 16384.0f));
}

extern "C" void kernel_launch(void* const* d_in, const int* in_sizes, int n_in,
                              void* d_out, int out_size, void* d_ws, size_t ws_size,
                              hipStream_t stream) {
    const float* x = (const float*)d_in[0];

    // Workspace: [0, 16 MiB) bf16 x; then 16384 x u64 argmax table.
    ushort* xb    = (ushort*)d_ws;
    u64*    table = (u64*)((char*)d_ws + (size_t)N_ROWS * DIM * sizeof(ushort));
    float*  out   = (float*)d_out;

    hipMemsetAsync(table, 0, N_ROWS * sizeof(u64), stream);
    hipMemsetAsync(out, 0, sizeof(float), stream);

    convert_bf16_kernel<<<2048, 256, 0, stream>>>(x, xb);
    argmax_dots_kernel<<<16384, 256, 0, stream>>>(xb, table);
    rho_loss_kernel<<<512, 256, 0, stream>>>(x, table, out);
}

// Round 3
// 368.628 us; speedup vs baseline: 3.1599x; 1.4995x over previous
//
#include <hip/hip_runtime.h>
#include <stdint.h>

#define N_ROWS 16384
#define DIM    512

typedef __bf16 v8bf __attribute__((ext_vector_type(8)));
typedef float  v4f  __attribute__((ext_vector_type(4)));
typedef unsigned long long u64;

union I4B8 { int4 i; v8bf b; };
__device__ __forceinline__ v8bf as_v8bf(int4 v) { I4B8 u; u.i = v; return u.b; }

// Round-to-nearest-even fp32 -> bf16
__device__ __forceinline__ ushort bf16_rne(float f) {
    unsigned u = __float_as_uint(f);
    unsigned r = u + 0x7FFFu + ((u >> 16) & 1u);
    return (ushort)(r >> 16);
}

// Monotonic float -> sortable u32 key
__device__ __forceinline__ unsigned fkey(float f) {
    unsigned u = __float_as_uint(f);
    return (u & 0x80000000u) ? ~u : (u | 0x80000000u);
}

// Async global->LDS, 16B per lane. LDS dest = wave-uniform base + lane*16.
__device__ __forceinline__ void gload_lds16(const void* g, void* l) {
    __builtin_amdgcn_global_load_lds(
        (const __attribute__((address_space(1))) unsigned int*)g,
        (__attribute__((address_space(3))) unsigned int*)l,
        16, 0, 0);
}

// ---------------- kernel 1: fp32 -> bf16 convert ----------------
__global__ __launch_bounds__(256)
void convert_bf16_kernel(const float* __restrict__ x, ushort* __restrict__ xb) {
    int tid    = blockIdx.x * blockDim.x + threadIdx.x;
    int stride = gridDim.x * blockDim.x;
    const float4* x4  = (const float4*)x;
    ushort4*      xb4 = (ushort4*)xb;
    const int n4 = (N_ROWS * DIM) / 4;
    for (int i = tid; i < n4; i += stride) {
        float4 v = x4[i];
        ushort4 o;
        o.x = bf16_rne(v.x);
        o.y = bf16_rne(v.y);
        o.z = bf16_rne(v.z);
        o.w = bf16_rne(v.w);
        xb4[i] = o;
    }
}

// ---------------- kernel 2: symmetric tiled GEMM + fused argmax ----------------
// Triangle-fold schedule: grid = 8256 blocks, b = u*64 + p (u in [0,129), p in [0,64)).
//   u <= p : (rT,cT) = (127-p, 127-u)     u > p : (rT,cT) = (p, u-1)
// Row pair (p,127-p) has a constant 129 tiles -> perfect balance; for fixed u all
// 64 blocks touch only 2 distinct B panels {u-1,127-u} -> B stays L2-hot; with
// blockIdx%8 XCD round-robin each XCD sees a fixed 16-row A set (2 MB, L2-resident).
// Block: 128x128 C tile, 4 waves (2x2 quadrants of 64x64), BK=64 LDS via
// global_load_lds width=16, m97 2-barrier K-loop. LDS chunk layout as before:
// L in [0,1024): row = (L>>9)*64 + ((L>>6)&3)*16 + (L&15); kchunk = ((L>>8)&1)*4 + ((L>>4)&3)
// -> every frag ds_read_b128 is base + lane*16: conflict-free.
__global__ __launch_bounds__(256)
void argmax_dots_kernel(const ushort* __restrict__ xb, u64* __restrict__ table) {
    __shared__ __attribute__((aligned(16))) ushort ldsA[128 * 64];  // 16 KB
    __shared__ __attribute__((aligned(16))) ushort ldsB[128 * 64];  // 16 KB

    const int u = blockIdx.x >> 6;
    const int p = blockIdx.x & 63;
    const int rT = (u <= p) ? (127 - p) : p;
    const int cT = (u <= p) ? (127 - u) : (u - 1);

    const int t      = threadIdx.x;
    const int lane   = t & 63;
    const int wave   = t >> 6;
    const int lane15 = lane & 15;
    const int quad   = lane >> 4;
    const int rh = wave >> 1;               // row half of the 128x128 tile
    const int ch = wave & 1;                // col half

    const int rowBase = rT * 128;
    const int colBase = cT * 128;

    // Per-thread staging sources for the 4 issues per matrix per round.
    const ushort* gA[4];
    const ushort* gB[4];
#pragma unroll
    for (int j = 0; j < 4; ++j) {
        const int L = j * 256 + t;
        const int srow = ((L >> 9) << 6) + (((L >> 6) & 3) << 4) + (L & 15);
        const int skc  = (((L >> 8) & 1) << 2) + ((L >> 4) & 3);
        gA[j] = xb + (size_t)(rowBase + srow) * DIM + skc * 8;
        gB[j] = xb + (size_t)(colBase + srow) * DIM + skc * 8;
    }
    const int dstOff = wave * 1024;         // + j*4096 per issue (bytes)

    v4f acc[4][4];
#pragma unroll
    for (int rf = 0; rf < 4; ++rf)
#pragma unroll
        for (int cf = 0; cf < 4; ++cf) {
            v4f z = {0.f, 0.f, 0.f, 0.f};
            acc[rf][cf] = z;
        }

    for (int kk = 0; kk < DIM; kk += 64) {  // 8 rounds
#pragma unroll
        for (int j = 0; j < 4; ++j) {
            gload_lds16(gA[j] + kk, (char*)ldsA + j * 4096 + dstOff);
            gload_lds16(gB[j] + kk, (char*)ldsB + j * 4096 + dstOff);
        }
        __syncthreads();                    // drains vmcnt, loads visible

#pragma unroll
        for (int s = 0; s < 2; ++s) {
            int4 ar[4], br[4];
#pragma unroll
            for (int rf = 0; rf < 4; ++rf)
                ar[rf] = *(const int4*)((const char*)ldsA + rh * 8192 + s * 4096 + rf * 1024 + lane * 16);
#pragma unroll
            for (int cf = 0; cf < 4; ++cf)
                br[cf] = *(const int4*)((const char*)ldsB + ch * 8192 + s * 4096 + cf * 1024 + lane * 16);
#pragma unroll
            for (int rf = 0; rf < 4; ++rf)
#pragma unroll
                for (int cf = 0; cf < 4; ++cf)
                    acc[rf][cf] = __builtin_amdgcn_mfma_f32_16x16x32_bf16(
                        as_v8bf(ar[rf]), as_v8bf(br[cf]), acc[rf][cf], 0, 0, 0);
        }
        __syncthreads();                    // protect LDS from next round's writes
    }

    // ---- epilogue: row-side argmax (C/D layout: col=lane15+16*cf, row=quad*4+e) ----
    const int colLane = colBase + ch * 64 + lane15;
#pragma unroll
    for (int rf = 0; rf < 4; ++rf) {
#pragma unroll
        for (int e = 0; e < 4; ++e) {
            const int row = rowBase + rh * 64 + rf * 16 + quad * 4 + e;
            float bv = -3.0e38f;
            int   bc = 0;
#pragma unroll
            for (int cf = 0; cf < 4; ++cf) {
                const float v = acc[rf][cf][e];
                const int col = colLane + cf * 16;
                if (v > bv && col != row) { bv = v; bc = col; }
            }
            u64 packed = ((u64)fkey(bv) << 32) | (unsigned)(~bc);  // ~col: ties -> lowest idx
#pragma unroll
            for (int m = 1; m < 16; m <<= 1) {
                u64 o = __shfl_xor(packed, m, 64);
                if (o > packed) packed = o;
            }
            if (lane15 == 0) atomicMax(&table[row], packed);
        }
    }

    // ---- epilogue: col-side (transposed) argmax for off-diagonal tiles ----
    if (rT != cT) {
#pragma unroll
        for (int cf = 0; cf < 4; ++cf) {
            const int col = colLane + cf * 16;
            float bv = -3.0e38f;
            int   br_ = 0;
#pragma unroll
            for (int rf = 0; rf < 4; ++rf)
#pragma unroll
                for (int e = 0; e < 4; ++e) {
                    const float v = acc[rf][cf][e];
                    const int row = rowBase + rh * 64 + rf * 16 + quad * 4 + e;
                    if (v > bv) { bv = v; br_ = row; }   // row != col off-diagonal
                }
            u64 packed = ((u64)fkey(bv) << 32) | (unsigned)(~br_);
            u64 o = __shfl_xor(packed, 16, 64); if (o > packed) packed = o;
            o     = __shfl_xor(packed, 32, 64); if (o > packed) packed = o;
            if (quad == 0) atomicMax(&table[col], packed);
        }
    }
}

// ---------------- kernel 3: rho + loss epilogue (fp32 exact) ----------------
__global__ __launch_bounds__(256)
void rho_loss_kernel(const float* __restrict__ x, const u64* __restrict__ table,
                     float* __restrict__ out) {
    const int lane = threadIdx.x & 63;
    const int wave = threadIdx.x >> 6;
    const int waveGlobal = blockIdx.x * 4 + wave;   // 2048 waves

    float local = 0.f;
    for (int r8 = 0; r8 < 8; ++r8) {
        const int row = waveGlobal * 8 + r8;
        const u64 packed = table[row];
        const int nb = (int)(~(unsigned)(packed & 0xFFFFFFFFu));

        const float4* xr = (const float4*)(x + (size_t)row * DIM);
        const float4* xn = (const float4*)(x + (size_t)nb  * DIM);
        float s = 0.f;
#pragma unroll
        for (int tt = 0; tt < 2; ++tt) {
            float4 a = xr[lane * 2 + tt];
            float4 b = xn[lane * 2 + tt];
            float d0 = a.x - b.x + 1e-6f;
            float d1 = a.y - b.y + 1e-6f;
            float d2 = a.z - b.z + 1e-6f;
            float d3 = a.w - b.w + 1e-6f;
            s += d0 * d0 + d1 * d1 + d2 * d2 + d3 * d3;
        }
#pragma unroll
        for (int m = 1; m < 64; m <<= 1) s += __shfl_xor(s, m, 64);

        if (lane == 0) {
            float rho = sqrtf(s);
            local += logf(rho + 1e-8f);
        }
    }
    if (lane == 0) atomicAdd(out, -local * (1.0f / 16384.0f));
}

extern "C" void kernel_launch(void* const* d_in, const int* in_sizes, int n_in,
                              void* d_out, int out_size, void* d_ws, size_t ws_size,
                              hipStream_t stream) {
    const float* x = (const float*)d_in[0];

    // Workspace: [0, 16 MiB) bf16 x; then 16384 x u64 argmax table.
    ushort* xb    = (ushort*)d_ws;
    u64*    table = (u64*)((char*)d_ws + (size_t)N_ROWS * DIM * sizeof(ushort));
    float*  out   = (float*)d_out;

    hipMemsetAsync(table, 0, N_ROWS * sizeof(u64), stream);
    hipMemsetAsync(out, 0, sizeof(float), stream);

    convert_bf16_kernel<<<2048, 256, 0, stream>>>(x, xb);
    argmax_dots_kernel<<<8256, 256, 0, stream>>>(xb, table);
    rho_loss_kernel<<<512, 256, 0, stream>>>(x, table, out);
}